// Round 3
// baseline (3521.621 us; speedup 1.0000x reference)
//
#include <hip/hip_runtime.h>
#include <math.h>

#define NBATCH 8
#define NTOK   4096
#define DIMX   512
#define QKVC   1536   // 3*8*64
#define DH     64
#define SCALE  0.125f // 64^-0.5

// ================= QKV GEMM: qkv[32768][1536] = x[32768][512] @ w[512][1536] =================
#define BM 128
#define BN 128
#define BK 16

__global__ __launch_bounds__(256) void qkv_gemm(const float* __restrict__ X,
                                                const float* __restrict__ W,
                                                float* __restrict__ QKV) {
    __shared__ float As[BK][BM + 4];
    __shared__ float Bs[BK][BN + 4];
    const int t  = threadIdx.x;
    const int tx = t & 15, ty = t >> 4;
    const int bm = blockIdx.x & 255;
    const int bn = blockIdx.x >> 8;
    const int m0 = bm * BM, n0 = bn * BN;

    float acc[8][8];
#pragma unroll
    for (int i = 0; i < 8; ++i)
#pragma unroll
        for (int j = 0; j < 8; ++j) acc[i][j] = 0.f;

    const int ar  = t >> 2, ak = (t & 3) << 2;
    const int bkr = t >> 5, bc = (t & 31) << 2;

    const float* Xp = X + (size_t)m0 * DIMX;
    const float* Wp = W + n0;

    for (int k0 = 0; k0 < DIMX; k0 += BK) {
        float4 a0 = *(const float4*)(Xp + (size_t)ar * DIMX + k0 + ak);
        float4 a1 = *(const float4*)(Xp + (size_t)(ar + 64) * DIMX + k0 + ak);
        float4 b0 = *(const float4*)(Wp + (size_t)(k0 + bkr) * QKVC + bc);
        float4 b1 = *(const float4*)(Wp + (size_t)(k0 + bkr + 8) * QKVC + bc);
        __syncthreads();
        As[ak+0][ar]    = a0.x; As[ak+1][ar]    = a0.y; As[ak+2][ar]    = a0.z; As[ak+3][ar]    = a0.w;
        As[ak+0][ar+64] = a1.x; As[ak+1][ar+64] = a1.y; As[ak+2][ar+64] = a1.z; As[ak+3][ar+64] = a1.w;
        *(float4*)&Bs[bkr][bc]     = b0;
        *(float4*)&Bs[bkr + 8][bc] = b1;
        __syncthreads();
#pragma unroll
        for (int kk = 0; kk < BK; ++kk) {
            float a[8], bb[8];
            *(float4*)&a[0]  = *(const float4*)&As[kk][ty * 4];
            *(float4*)&a[4]  = *(const float4*)&As[kk][64 + ty * 4];
            *(float4*)&bb[0] = *(const float4*)&Bs[kk][tx * 4];
            *(float4*)&bb[4] = *(const float4*)&Bs[kk][64 + tx * 4];
#pragma unroll
            for (int i = 0; i < 8; ++i)
#pragma unroll
                for (int j = 0; j < 8; ++j) acc[i][j] = fmaf(a[i], bb[j], acc[i][j]);
        }
    }
#pragma unroll
    for (int i = 0; i < 8; ++i) {
        int r = m0 + ((i < 4) ? (ty * 4 + i) : (64 + ty * 4 + i - 4));
        float* o = QKV + (size_t)r * QKVC + n0;
        *(float4*)(o + tx * 4)      = make_float4(acc[i][0], acc[i][1], acc[i][2], acc[i][3]);
        *(float4*)(o + 64 + tx * 4) = make_float4(acc[i][4], acc[i][5], acc[i][6], acc[i][7]);
    }
}

// ================= Spatial attention: heads 0..3, per frame over 256 tokens ==============
// Round-2 post-mortem: VGPR hit 256 + 1.9 GB scratch writes. Fixes:
//   * SCHK 32->16 (s[16] live range), __launch_bounds__(512,4) caps VGPR at 128.
//   * 512-thread block = 128 query rows share one 64 KB K tile; LDS 72 KB ->
//     2 blocks/CU * 8 waves = 16 waves/CU (matches 128-VGPR budget).
// 4 lanes per row (lane l owns dims l*16..+15): q[16]+acc[16]+s[16] = 48 floats.
#define SCHK 16
__global__ __launch_bounds__(512, 4) void attn_spatial(const float* __restrict__ QKV,
                                                       float* __restrict__ Out) {
    __shared__ float Ks[256][DH];           // 64 KiB
    __shared__ float Vs[2][SCHK][DH];       // 8 KiB
    const int t    = threadIdx.x;
    const int half = blockIdx.x & 1;
    const int nt   = (blockIdx.x >> 1) & 15;
    const int h    = (blockIdx.x >> 5) & 3;
    const int b    = blockIdx.x >> 7;
    const int base = nt * 256;
    const int l    = t & 3;                 // dim-slice in quad
    const int row  = half * 128 + (t >> 2); // query row 0..255
    const size_t rowoff = (size_t)b * NTOK;

    const float* Kg = QKV + (rowoff + base) * QKVC + 512  + h * DH;
    const float* Vg = QKV + (rowoff + base) * QKVC + 1024 + h * DH;
    const float* Qg = QKV + (rowoff + base + row) * QKVC + h * DH + l * 16;

    // stage K tile [256][64]: 4096 float4 / 512 threads = 8 iters
#pragma unroll
    for (int i = 0; i < 8; ++i) {
        int idx = t + 512 * i;
        int kr = idx >> 4, c4 = (idx & 15) << 2;
        *(float4*)&Ks[kr][c4] = *(const float4*)(Kg + (size_t)kr * QKVC + c4);
    }
    // stage V chunk 0: 1024 floats / 512 threads = 1 float2 each
    {
        int vr = t >> 5, c2 = (t & 31) << 1;
        *(float2*)&Vs[0][vr][c2] = *(const float2*)(Vg + (size_t)vr * QKVC + c2);
    }

    float q[16];
#pragma unroll
    for (int c = 0; c < 16; c += 4) *(float4*)&q[c] = *(const float4*)(Qg + c);

    float acc[16];
#pragma unroll
    for (int c = 0; c < 16; ++c) acc[c] = 0.f;
    float m = -INFINITY, lsum = 0.f;

    __syncthreads();

    for (int ch = 0; ch < 16; ++ch) {
        float s[SCHK];
        float cmax = -INFINITY;
#pragma unroll
        for (int j = 0; j < SCHK; ++j) {
            const float* kr = &Ks[ch * SCHK + j][l * 16];
            float d = 0.f;
#pragma unroll
            for (int c = 0; c < 16; c += 4) {
                float4 kv = *(const float4*)&kr[c];
                d = fmaf(q[c], kv.x, d); d = fmaf(q[c+1], kv.y, d);
                d = fmaf(q[c+2], kv.z, d); d = fmaf(q[c+3], kv.w, d);
            }
            d += __shfl_xor(d, 1, 4);     // quad reduce
            d += __shfl_xor(d, 2, 4);
            s[j] = d * SCALE;
            cmax = fmaxf(cmax, s[j]);
        }
        float mn   = fmaxf(m, cmax);
        float corr = __expf(m - mn);      // first chunk: exp(-inf)=0, acc already 0
        float psum = 0.f;
#pragma unroll
        for (int j = 0; j < SCHK; ++j) { s[j] = __expf(s[j] - mn); psum += s[j]; }
        lsum = lsum * corr + psum;
        m = mn;
#pragma unroll
        for (int c = 0; c < 16; ++c) acc[c] *= corr;

        // prefetch next V chunk into regs (hide HBM latency under PV)
        float2 v0;
        int vr = t >> 5, c2 = (t & 31) << 1;
        if (ch + 1 < 16)
            v0 = *(const float2*)(Vg + (size_t)((ch + 1) * SCHK + vr) * QKVC + c2);

        // PV accumulate (this lane's 16-dim slice)
#pragma unroll
        for (int j = 0; j < SCHK; ++j) {
            const float* vrp = &Vs[ch & 1][j][l * 16];
            float p = s[j];
#pragma unroll
            for (int c = 0; c < 16; c += 4) {
                float4 vv = *(const float4*)&vrp[c];
                acc[c]   = fmaf(p, vv.x, acc[c]);   acc[c+1] = fmaf(p, vv.y, acc[c+1]);
                acc[c+2] = fmaf(p, vv.z, acc[c+2]); acc[c+3] = fmaf(p, vv.w, acc[c+3]);
            }
        }
        if (ch + 1 < 16)
            *(float2*)&Vs[(ch + 1) & 1][vr][c2] = v0;
        __syncthreads();
    }

    float inv = 1.f / lsum;
    float* op = Out + ((size_t)(b * 4 + h) * NTOK + base + row) * DH + l * 16;
#pragma unroll
    for (int c = 0; c < 16; c += 4)
        *(float4*)(op + c) = make_float4(acc[c]*inv, acc[c+1]*inv, acc[c+2]*inv, acc[c+3]*inv);
}

// ================= Temporal attention: heads 4..7, per spatial pos over 16 frames =============
// Quad-split like spatial (round-2 version held q[64]+acc[64]+sc[16]=144 floats -> spill risk).
// Wave = 16 consecutive rows = the 16 tokens of one s-group -> K/V addresses shared across
// rows, 4 distinct 64B slices per key -> fully coalesced.
__global__ __launch_bounds__(256, 4) void attn_temporal(const float* __restrict__ QKV,
                                                        float* __restrict__ Out) {
    const int t    = threadIdx.x;
    const int l    = t & 3;
    const int row  = blockIdx.x * 64 + (t >> 2);  // 0..131071
    const int tt   = row & 15;
    const int s    = (row >> 4) & 255;
    const int h    = (row >> 12) & 3;
    const int b    = row >> 14;
    const int head = 4 + h;
    const int token = s * 16 + tt;
    const size_t rowoff = (size_t)b * NTOK;

    const float* Qp = QKV + (rowoff + token) * QKVC + head * DH + l * 16;
    const float* Kb = QKV + (rowoff + s * 16) * QKVC + 512  + head * DH + l * 16;
    const float* Vb = QKV + (rowoff + s * 16) * QKVC + 1024 + head * DH + l * 16;

    float q[16];
#pragma unroll
    for (int c = 0; c < 16; c += 4) *(float4*)&q[c] = *(const float4*)(Qp + c);

    float sc[16];
    float mx = -INFINITY;
#pragma unroll
    for (int j = 0; j < 16; ++j) {
        const float* kr = Kb + (size_t)j * QKVC;
        float d = 0.f;
#pragma unroll
        for (int c = 0; c < 16; c += 4) {
            float4 kv = *(const float4*)(kr + c);
            d = fmaf(q[c], kv.x, d); d = fmaf(q[c+1], kv.y, d);
            d = fmaf(q[c+2], kv.z, d); d = fmaf(q[c+3], kv.w, d);
        }
        d += __shfl_xor(d, 1, 4);
        d += __shfl_xor(d, 2, 4);
        sc[j] = d * SCALE;
        mx = fmaxf(mx, sc[j]);
    }
    float lsum = 0.f;
#pragma unroll
    for (int j = 0; j < 16; ++j) { sc[j] = __expf(sc[j] - mx); lsum += sc[j]; }
    float inv = 1.f / lsum;

    float acc[16];
#pragma unroll
    for (int c = 0; c < 16; ++c) acc[c] = 0.f;
#pragma unroll
    for (int j = 0; j < 16; ++j) {
        const float* vr = Vb + (size_t)j * QKVC;
        float p = sc[j];
#pragma unroll
        for (int c = 0; c < 16; c += 4) {
            float4 vv = *(const float4*)(vr + c);
            acc[c]   = fmaf(p, vv.x, acc[c]);   acc[c+1] = fmaf(p, vv.y, acc[c+1]);
            acc[c+2] = fmaf(p, vv.z, acc[c+2]); acc[c+3] = fmaf(p, vv.w, acc[c+3]);
        }
    }
    float* op = Out + (size_t)(NBATCH * 4) * NTOK * DH
                    + ((size_t)(b * 4 + h) * NTOK + token) * DH + l * 16;
#pragma unroll
    for (int c = 0; c < 16; c += 4)
        *(float4*)(op + c) = make_float4(acc[c]*inv, acc[c+1]*inv, acc[c+2]*inv, acc[c+3]*inv);
}

extern "C" void kernel_launch(void* const* d_in, const int* in_sizes, int n_in,
                              void* d_out, int out_size, void* d_ws, size_t ws_size,
                              hipStream_t stream) {
    const float* x = (const float*)d_in[0];   // [8,4096,512] fp32
    const float* w = (const float*)d_in[1];   // [512,1536]  fp32
    float* out = (float*)d_out;               // [2,8,4,4096,64] fp32
    float* qkv = (float*)d_ws;                // 8*4096*1536*4 = 192 MiB scratch

    qkv_gemm<<<dim3(256 * 12), 256, 0, stream>>>(x, w, qkv);
    attn_spatial<<<dim3(1024), 512, 0, stream>>>(qkv, out);
    attn_temporal<<<dim3(2048), 256, 0, stream>>>(qkv, out);
}

// Round 10
// 911.857 us; speedup vs baseline: 3.8620x; 3.8620x over previous
//
#include <hip/hip_runtime.h>
#include <math.h>

#define NBATCH 8
#define NTOK   4096
#define DIMX   512
#define QKVC   1536   // 3*8*64
#define DH     64
#define SCALE  0.125f // 64^-0.5

// ================= QKV GEMM: qkv[32768][1536] = x[32768][512] @ w[512][1536] =================
#define BM 128
#define BN 128
#define BK 16

__global__ __launch_bounds__(256) void qkv_gemm(const float* __restrict__ X,
                                                const float* __restrict__ W,
                                                float* __restrict__ QKV) {
    __shared__ float As[BK][BM + 4];
    __shared__ float Bs[BK][BN + 4];
    const int t  = threadIdx.x;
    const int tx = t & 15, ty = t >> 4;
    const int bm = blockIdx.x & 255;
    const int bn = blockIdx.x >> 8;
    const int m0 = bm * BM, n0 = bn * BN;

    float acc[8][8];
#pragma unroll
    for (int i = 0; i < 8; ++i)
#pragma unroll
        for (int j = 0; j < 8; ++j) acc[i][j] = 0.f;

    const int ar  = t >> 2, ak = (t & 3) << 2;
    const int bkr = t >> 5, bc = (t & 31) << 2;

    const float* Xp = X + (size_t)m0 * DIMX;
    const float* Wp = W + n0;

    for (int k0 = 0; k0 < DIMX; k0 += BK) {
        float4 a0 = *(const float4*)(Xp + (size_t)ar * DIMX + k0 + ak);
        float4 a1 = *(const float4*)(Xp + (size_t)(ar + 64) * DIMX + k0 + ak);
        float4 b0 = *(const float4*)(Wp + (size_t)(k0 + bkr) * QKVC + bc);
        float4 b1 = *(const float4*)(Wp + (size_t)(k0 + bkr + 8) * QKVC + bc);
        __syncthreads();
        As[ak+0][ar]    = a0.x; As[ak+1][ar]    = a0.y; As[ak+2][ar]    = a0.z; As[ak+3][ar]    = a0.w;
        As[ak+0][ar+64] = a1.x; As[ak+1][ar+64] = a1.y; As[ak+2][ar+64] = a1.z; As[ak+3][ar+64] = a1.w;
        *(float4*)&Bs[bkr][bc]     = b0;
        *(float4*)&Bs[bkr + 8][bc] = b1;
        __syncthreads();
#pragma unroll
        for (int kk = 0; kk < BK; ++kk) {
            float a[8], bb[8];
            *(float4*)&a[0]  = *(const float4*)&As[kk][ty * 4];
            *(float4*)&a[4]  = *(const float4*)&As[kk][64 + ty * 4];
            *(float4*)&bb[0] = *(const float4*)&Bs[kk][tx * 4];
            *(float4*)&bb[4] = *(const float4*)&Bs[kk][64 + tx * 4];
#pragma unroll
            for (int i = 0; i < 8; ++i)
#pragma unroll
                for (int j = 0; j < 8; ++j) acc[i][j] = fmaf(a[i], bb[j], acc[i][j]);
        }
    }
#pragma unroll
    for (int i = 0; i < 8; ++i) {
        int r = m0 + ((i < 4) ? (ty * 4 + i) : (64 + ty * 4 + i - 4));
        float* o = QKV + (size_t)r * QKVC + n0;
        *(float4*)(o + tx * 4)      = make_float4(acc[i][0], acc[i][1], acc[i][2], acc[i][3]);
        *(float4*)(o + 64 + tx * 4) = make_float4(acc[i][4], acc[i][5], acc[i][6], acc[i][7]);
    }
}

// ================= Spatial attention: heads 0..3, per frame over 256 tokens ==============
// Rounds 1-3 all lost to register spill (scratch traffic signature: huge WRITE_SIZE,
// tiny VALUBusy). Fix philosophy this round: NOTHING the allocator can spill.
//   * all per-thread state is NAMED float4/scalars (qa..qd, ac0..3, s0..s7)
//   * 1024-thread block = one whole 256-row tile; K AND V fully LDS-resident
//     (128 KiB) -> single __syncthreads, no double-buffering, K/V HBM-read once.
//   * 4 lanes per row: lane l owns dims l*16..l*16+15; quad shfl_xor for dots.
//   * 16 waves/block -> 4 waves/SIMD residency floor -> HW-forced <=128 VGPR cap.

#define QDOT(JJ, SREG) do {                                                     \
    const float* kr_ = &Ks[k0 + (JJ)][l16];                                     \
    float4 ka_ = *(const float4*)(kr_);      float4 kb_ = *(const float4*)(kr_ + 4);  \
    float4 kc_ = *(const float4*)(kr_ + 8);  float4 kd_ = *(const float4*)(kr_ + 12); \
    float d_ = qa.x * ka_.x;                                                    \
    d_ = fmaf(qa.y, ka_.y, d_); d_ = fmaf(qa.z, ka_.z, d_); d_ = fmaf(qa.w, ka_.w, d_); \
    d_ = fmaf(qb.x, kb_.x, d_); d_ = fmaf(qb.y, kb_.y, d_); d_ = fmaf(qb.z, kb_.z, d_); d_ = fmaf(qb.w, kb_.w, d_); \
    d_ = fmaf(qc.x, kc_.x, d_); d_ = fmaf(qc.y, kc_.y, d_); d_ = fmaf(qc.z, kc_.z, d_); d_ = fmaf(qc.w, kc_.w, d_); \
    d_ = fmaf(qd.x, kd_.x, d_); d_ = fmaf(qd.y, kd_.y, d_); d_ = fmaf(qd.z, kd_.z, d_); d_ = fmaf(qd.w, kd_.w, d_); \
    d_ += __shfl_xor(d_, 1, 4);  d_ += __shfl_xor(d_, 2, 4);                    \
    SREG = d_ * SCALE;                                                          \
} while (0)

#define PVACC(JJ, P) do {                                                       \
    const float* vr_ = &Vs[k0 + (JJ)][l16];                                     \
    float4 va_ = *(const float4*)(vr_);      float4 vb_ = *(const float4*)(vr_ + 4);  \
    float4 vc_ = *(const float4*)(vr_ + 8);  float4 vd_ = *(const float4*)(vr_ + 12); \
    ac0.x = fmaf((P), va_.x, ac0.x); ac0.y = fmaf((P), va_.y, ac0.y);           \
    ac0.z = fmaf((P), va_.z, ac0.z); ac0.w = fmaf((P), va_.w, ac0.w);           \
    ac1.x = fmaf((P), vb_.x, ac1.x); ac1.y = fmaf((P), vb_.y, ac1.y);           \
    ac1.z = fmaf((P), vb_.z, ac1.z); ac1.w = fmaf((P), vb_.w, ac1.w);           \
    ac2.x = fmaf((P), vc_.x, ac2.x); ac2.y = fmaf((P), vc_.y, ac2.y);           \
    ac2.z = fmaf((P), vc_.z, ac2.z); ac2.w = fmaf((P), vc_.w, ac2.w);           \
    ac3.x = fmaf((P), vd_.x, ac3.x); ac3.y = fmaf((P), vd_.y, ac3.y);           \
    ac3.z = fmaf((P), vd_.z, ac3.z); ac3.w = fmaf((P), vd_.w, ac3.w);           \
} while (0)

__global__ __launch_bounds__(1024, 1) void attn_spatial(const float* __restrict__ QKV,
                                                        float* __restrict__ Out) {
    __shared__ float Ks[256][DH];   // 64 KiB
    __shared__ float Vs[256][DH];   // 64 KiB
    const int t    = threadIdx.x;
    const int nt   = blockIdx.x & 15;
    const int h    = (blockIdx.x >> 4) & 3;
    const int b    = blockIdx.x >> 6;
    const int base = nt * 256;
    const int l16  = (t & 3) * 16;   // dim-slice offset within the quad
    const int row  = t >> 2;         // query row 0..255
    const size_t rowoff = (size_t)b * NTOK;

    const float* Kg = QKV + (rowoff + base) * QKVC + 512  + h * DH;
    const float* Vg = QKV + (rowoff + base) * QKVC + 1024 + h * DH;
    const float* Qg = QKV + (rowoff + base + row) * QKVC + h * DH + l16;

    // stage K and V tiles [256][64]: 4096 float4 each / 1024 threads = 4 iters
#pragma unroll
    for (int i = 0; i < 4; ++i) {
        int idx = t + 1024 * i;
        int r = idx >> 4, c4 = (idx & 15) << 2;
        *(float4*)&Ks[r][c4] = *(const float4*)(Kg + (size_t)r * QKVC + c4);
        *(float4*)&Vs[r][c4] = *(const float4*)(Vg + (size_t)r * QKVC + c4);
    }

    float4 qa = *(const float4*)(Qg);
    float4 qb = *(const float4*)(Qg + 4);
    float4 qc = *(const float4*)(Qg + 8);
    float4 qd = *(const float4*)(Qg + 12);

    float4 ac0 = make_float4(0.f, 0.f, 0.f, 0.f);
    float4 ac1 = ac0, ac2 = ac0, ac3 = ac0;
    float m = -INFINITY, lsum = 0.f;

    __syncthreads();

    for (int k0 = 0; k0 < 256; k0 += 8) {
        float s0, s1, s2, s3, s4, s5, s6, s7;
        QDOT(0, s0); QDOT(1, s1); QDOT(2, s2); QDOT(3, s3);
        QDOT(4, s4); QDOT(5, s5); QDOT(6, s6); QDOT(7, s7);

        float cmax = fmaxf(fmaxf(fmaxf(s0, s1), fmaxf(s2, s3)),
                           fmaxf(fmaxf(s4, s5), fmaxf(s6, s7)));
        float mn   = fmaxf(m, cmax);
        float corr = __expf(m - mn);    // first chunk: exp(-inf)=0, acc already 0
        s0 = __expf(s0 - mn); s1 = __expf(s1 - mn); s2 = __expf(s2 - mn); s3 = __expf(s3 - mn);
        s4 = __expf(s4 - mn); s5 = __expf(s5 - mn); s6 = __expf(s6 - mn); s7 = __expf(s7 - mn);
        float psum = ((s0 + s1) + (s2 + s3)) + ((s4 + s5) + (s6 + s7));
        lsum = fmaf(lsum, corr, psum);
        m = mn;
        ac0.x *= corr; ac0.y *= corr; ac0.z *= corr; ac0.w *= corr;
        ac1.x *= corr; ac1.y *= corr; ac1.z *= corr; ac1.w *= corr;
        ac2.x *= corr; ac2.y *= corr; ac2.z *= corr; ac2.w *= corr;
        ac3.x *= corr; ac3.y *= corr; ac3.z *= corr; ac3.w *= corr;

        PVACC(0, s0); PVACC(1, s1); PVACC(2, s2); PVACC(3, s3);
        PVACC(4, s4); PVACC(5, s5); PVACC(6, s6); PVACC(7, s7);
    }

    float inv = 1.f / lsum;
    float* op = Out + ((size_t)(b * 4 + h) * NTOK + base + row) * DH + l16;
    *(float4*)(op)      = make_float4(ac0.x * inv, ac0.y * inv, ac0.z * inv, ac0.w * inv);
    *(float4*)(op + 4)  = make_float4(ac1.x * inv, ac1.y * inv, ac1.z * inv, ac1.w * inv);
    *(float4*)(op + 8)  = make_float4(ac2.x * inv, ac2.y * inv, ac2.z * inv, ac2.w * inv);
    *(float4*)(op + 12) = make_float4(ac3.x * inv, ac3.y * inv, ac3.z * inv, ac3.w * inv);
}

// ================= Temporal attention: heads 4..7, per spatial pos over 16 frames =============
// Quad-split; wave = 16 consecutive rows = 16 tokens of one s-group -> K/V addresses
// shared across rows (HW merges), 48 floats of state. (256,4): VGPR cap 128 under
// either launch_bounds semantics.
__global__ __launch_bounds__(256, 4) void attn_temporal(const float* __restrict__ QKV,
                                                        float* __restrict__ Out) {
    const int t    = threadIdx.x;
    const int l    = t & 3;
    const int row  = blockIdx.x * 64 + (t >> 2);  // 0..131071
    const int tt   = row & 15;
    const int s    = (row >> 4) & 255;
    const int h    = (row >> 12) & 3;
    const int b    = row >> 14;
    const int head = 4 + h;
    const int token = s * 16 + tt;
    const size_t rowoff = (size_t)b * NTOK;

    const float* Qp = QKV + (rowoff + token) * QKVC + head * DH + l * 16;
    const float* Kb = QKV + (rowoff + s * 16) * QKVC + 512  + head * DH + l * 16;
    const float* Vb = QKV + (rowoff + s * 16) * QKVC + 1024 + head * DH + l * 16;

    float q[16];
#pragma unroll
    for (int c = 0; c < 16; c += 4) *(float4*)&q[c] = *(const float4*)(Qp + c);

    float sc[16];
    float mx = -INFINITY;
#pragma unroll
    for (int j = 0; j < 16; ++j) {
        const float* kr = Kb + (size_t)j * QKVC;
        float d = 0.f;
#pragma unroll
        for (int c = 0; c < 16; c += 4) {
            float4 kv = *(const float4*)(kr + c);
            d = fmaf(q[c], kv.x, d); d = fmaf(q[c+1], kv.y, d);
            d = fmaf(q[c+2], kv.z, d); d = fmaf(q[c+3], kv.w, d);
        }
        d += __shfl_xor(d, 1, 4);
        d += __shfl_xor(d, 2, 4);
        sc[j] = d * SCALE;
        mx = fmaxf(mx, sc[j]);
    }
    float lsum = 0.f;
#pragma unroll
    for (int j = 0; j < 16; ++j) { sc[j] = __expf(sc[j] - mx); lsum += sc[j]; }
    float inv = 1.f / lsum;

    float acc[16];
#pragma unroll
    for (int c = 0; c < 16; ++c) acc[c] = 0.f;
#pragma unroll
    for (int j = 0; j < 16; ++j) {
        const float* vr = Vb + (size_t)j * QKVC;
        float p = sc[j];
#pragma unroll
        for (int c = 0; c < 16; c += 4) {
            float4 vv = *(const float4*)(vr + c);
            acc[c]   = fmaf(p, vv.x, acc[c]);   acc[c+1] = fmaf(p, vv.y, acc[c+1]);
            acc[c+2] = fmaf(p, vv.z, acc[c+2]); acc[c+3] = fmaf(p, vv.w, acc[c+3]);
        }
    }
    float* op = Out + (size_t)(NBATCH * 4) * NTOK * DH
                    + ((size_t)(b * 4 + h) * NTOK + token) * DH + l * 16;
#pragma unroll
    for (int c = 0; c < 16; c += 4)
        *(float4*)(op + c) = make_float4(acc[c]*inv, acc[c+1]*inv, acc[c+2]*inv, acc[c+3]*inv);
}

extern "C" void kernel_launch(void* const* d_in, const int* in_sizes, int n_in,
                              void* d_out, int out_size, void* d_ws, size_t ws_size,
                              hipStream_t stream) {
    const float* x = (const float*)d_in[0];   // [8,4096,512] fp32
    const float* w = (const float*)d_in[1];   // [512,1536]  fp32
    float* out = (float*)d_out;               // [2,8,4,4096,64] fp32
    float* qkv = (float*)d_ws;                // 8*4096*1536*4 = 192 MiB scratch

    qkv_gemm<<<dim3(256 * 12), 256, 0, stream>>>(x, w, qkv);
    attn_spatial<<<dim3(512), 1024, 0, stream>>>(qkv, out);
    attn_temporal<<<dim3(2048), 256, 0, stream>>>(qkv, out);
}

// Round 13
// 623.435 us; speedup vs baseline: 5.6487x; 1.4626x over previous
//
#include <hip/hip_runtime.h>
#include <math.h>

#define NBATCH 8
#define NTOK   4096
#define DIMX   512
#define QKVC   1536   // 3*8*64
#define DH     64
#define SCALE  0.125f // 64^-0.5

typedef __attribute__((ext_vector_type(8))) short short8;
typedef __attribute__((ext_vector_type(4))) float f32x4;

// ============== QKV GEMM via MFMA, split-bf16 (fp32-level accuracy) ==============
// C = X*W with x=xh+xl, w=wh+wl (bf16 each, on-the-fly split in staging):
//   acc += xh*wh + xh*wl + xl*wh   (xl*wl ~ 2^-18 rel, dropped)
// Tile 128x128, BK=64, 4 waves (2x2 of 64x64). LDS: Ah/Al[row][k], Bh/Bl[col][k]
// (B stored TRANSPOSED so fragments are contiguous), all XOR-swizzled
// (short-idx ^= (row&7)<<3) -> every b128 read/write is conflict-free.
// mfma_f32_16x16x32_bf16 layouts (HW-verified per guide):
//   A: row=lane&15, k=(lane>>4)*8+j ; B: col=lane&15, k=(lane>>4)*8+j
//   C/D: col=lane&15, row=(lane>>4)*4+reg

static __device__ __forceinline__ unsigned short f2bf_hi(float f) {
    unsigned u = __float_as_uint(f);
    return (unsigned short)((u + 0x8000u) >> 16);   // round-half-up, fine for N(0,1) data
}
static __device__ __forceinline__ unsigned short f2bf_lo(float f, unsigned short hi) {
    float hf = __uint_as_float(((unsigned)hi) << 16);
    return (unsigned short)(__float_as_uint(f - hf) >> 16);  // truncate residual
}

// pack 8 consecutive k (two float4) into hi/lo short8
#define BF_PACK2(H, L, F0, F1) do {                                             \
    unsigned short h0=f2bf_hi(F0.x),h1=f2bf_hi(F0.y),h2=f2bf_hi(F0.z),h3=f2bf_hi(F0.w); \
    unsigned short h4=f2bf_hi(F1.x),h5=f2bf_hi(F1.y),h6=f2bf_hi(F1.z),h7=f2bf_hi(F1.w); \
    H[0]=(short)h0; H[1]=(short)h1; H[2]=(short)h2; H[3]=(short)h3;             \
    H[4]=(short)h4; H[5]=(short)h5; H[6]=(short)h6; H[7]=(short)h7;             \
    L[0]=(short)f2bf_lo(F0.x,h0); L[1]=(short)f2bf_lo(F0.y,h1);                 \
    L[2]=(short)f2bf_lo(F0.z,h2); L[3]=(short)f2bf_lo(F0.w,h3);                 \
    L[4]=(short)f2bf_lo(F1.x,h4); L[5]=(short)f2bf_lo(F1.y,h5);                 \
    L[6]=(short)f2bf_lo(F1.z,h6); L[7]=(short)f2bf_lo(F1.w,h7);                 \
} while (0)

// pack component C of lb0..lb7 (8 k-rows, one col) into hi/lo short8
#define BF_PACKC(H, L, C) do {                                                  \
    unsigned short h0=f2bf_hi(lb0.C),h1=f2bf_hi(lb1.C),h2=f2bf_hi(lb2.C),h3=f2bf_hi(lb3.C); \
    unsigned short h4=f2bf_hi(lb4.C),h5=f2bf_hi(lb5.C),h6=f2bf_hi(lb6.C),h7=f2bf_hi(lb7.C); \
    H[0]=(short)h0; H[1]=(short)h1; H[2]=(short)h2; H[3]=(short)h3;             \
    H[4]=(short)h4; H[5]=(short)h5; H[6]=(short)h6; H[7]=(short)h7;             \
    L[0]=(short)f2bf_lo(lb0.C,h0); L[1]=(short)f2bf_lo(lb1.C,h1);               \
    L[2]=(short)f2bf_lo(lb2.C,h2); L[3]=(short)f2bf_lo(lb3.C,h3);               \
    L[4]=(short)f2bf_lo(lb4.C,h4); L[5]=(short)f2bf_lo(lb5.C,h5);               \
    L[6]=(short)f2bf_lo(lb6.C,h6); L[7]=(short)f2bf_lo(lb7.C,h7);               \
} while (0)

__global__ __launch_bounds__(256, 2) void qkv_gemm_mfma(const float* __restrict__ X,
                                                        const float* __restrict__ W,
                                                        float* __restrict__ QKV) {
    __shared__ short Ah[128 * 64];   // 16 KB each, 64 KB total
    __shared__ short Al[128 * 64];
    __shared__ short Bh[128 * 64];   // [col][k] (transposed W)
    __shared__ short Bl[128 * 64];

    const int t    = threadIdx.x;
    const int bm   = blockIdx.x & 255;   // 32768/128 = 256 row tiles
    const int bn   = blockIdx.x >> 8;    // 1536/128  = 12 col tiles
    const int m0   = bm * 128, n0 = bn * 128;
    const int lane = t & 63;
    const int wv   = t >> 6, wr = wv >> 1, wc = wv & 1;  // 2x2 waves, 64x64 each
    const int lr   = lane & 15, kg4 = lane >> 4;

    // staging roles (all 256 threads)
    const int arow = t >> 1, ahalf = t & 1;   // A: one row-half (32 floats)
    const int bkg  = t & 7,  bcg   = t >> 3;  // B: 8 k-rows x 4 cols

    f32x4 acc[4][4];
#pragma unroll
    for (int i = 0; i < 4; ++i)
#pragma unroll
        for (int j = 0; j < 4; ++j) acc[i][j] = (f32x4){0.f, 0.f, 0.f, 0.f};

    const float* Xp = X + (size_t)(m0 + arow) * DIMX + ahalf * 32;
    const float* Wp = W + (size_t)bkg * 8 * QKVC + n0 + bcg * 4;

    for (int k0 = 0; k0 < DIMX; k0 += 64) {
        // ---- global loads (issued before the barrier so they overlap prior compute)
        float4 la0 = *(const float4*)(Xp + k0 +  0);
        float4 la1 = *(const float4*)(Xp + k0 +  4);
        float4 la2 = *(const float4*)(Xp + k0 +  8);
        float4 la3 = *(const float4*)(Xp + k0 + 12);
        float4 la4 = *(const float4*)(Xp + k0 + 16);
        float4 la5 = *(const float4*)(Xp + k0 + 20);
        float4 la6 = *(const float4*)(Xp + k0 + 24);
        float4 la7 = *(const float4*)(Xp + k0 + 28);
        const float* Wk = Wp + (size_t)k0 * QKVC;
        float4 lb0 = *(const float4*)(Wk + 0 * QKVC);
        float4 lb1 = *(const float4*)(Wk + 1 * QKVC);
        float4 lb2 = *(const float4*)(Wk + 2 * QKVC);
        float4 lb3 = *(const float4*)(Wk + 3 * QKVC);
        float4 lb4 = *(const float4*)(Wk + 4 * QKVC);
        float4 lb5 = *(const float4*)(Wk + 5 * QKVC);
        float4 lb6 = *(const float4*)(Wk + 6 * QKVC);
        float4 lb7 = *(const float4*)(Wk + 7 * QKVC);

        __syncthreads();   // previous iteration's fragment reads done

        // ---- A: 4 chunks of 8 k, hi+lo, swizzled b128 stores
        {
            const int sw = (arow & 7) << 3;
            short8 H, L;
            BF_PACK2(H, L, la0, la1);
            { int idx = arow * 64 + ((ahalf * 32 +  0) ^ sw);
              *(short8*)&Ah[idx] = H; *(short8*)&Al[idx] = L; }
            BF_PACK2(H, L, la2, la3);
            { int idx = arow * 64 + ((ahalf * 32 +  8) ^ sw);
              *(short8*)&Ah[idx] = H; *(short8*)&Al[idx] = L; }
            BF_PACK2(H, L, la4, la5);
            { int idx = arow * 64 + ((ahalf * 32 + 16) ^ sw);
              *(short8*)&Ah[idx] = H; *(short8*)&Al[idx] = L; }
            BF_PACK2(H, L, la6, la7);
            { int idx = arow * 64 + ((ahalf * 32 + 24) ^ sw);
              *(short8*)&Ah[idx] = H; *(short8*)&Al[idx] = L; }
        }
        // ---- B: 4 cols, transpose during pack, swizzled b128 stores
        {
            short8 H, L;
            { int col = bcg * 4 + 0; int idx = col * 64 + ((bkg * 8) ^ ((col & 7) << 3));
              BF_PACKC(H, L, x); *(short8*)&Bh[idx] = H; *(short8*)&Bl[idx] = L; }
            { int col = bcg * 4 + 1; int idx = col * 64 + ((bkg * 8) ^ ((col & 7) << 3));
              BF_PACKC(H, L, y); *(short8*)&Bh[idx] = H; *(short8*)&Bl[idx] = L; }
            { int col = bcg * 4 + 2; int idx = col * 64 + ((bkg * 8) ^ ((col & 7) << 3));
              BF_PACKC(H, L, z); *(short8*)&Bh[idx] = H; *(short8*)&Bl[idx] = L; }
            { int col = bcg * 4 + 3; int idx = col * 64 + ((bkg * 8) ^ ((col & 7) << 3));
              BF_PACKC(H, L, w); *(short8*)&Bh[idx] = H; *(short8*)&Bl[idx] = L; }
        }
        __syncthreads();   // tile ready

        // ---- 2 k-slices x 3 products x 16 fragments = 96 MFMA / wave / step
#pragma unroll
        for (int ks = 0; ks < 2; ++ks) {
            short8 a_h[4], a_l[4], b_h[4], b_l[4];
#pragma unroll
            for (int fm = 0; fm < 4; ++fm) {
                int row = wr * 64 + fm * 16 + lr;
                int idx = row * 64 + ((ks * 32 + kg4 * 8) ^ ((row & 7) << 3));
                a_h[fm] = *(const short8*)&Ah[idx];
                a_l[fm] = *(const short8*)&Al[idx];
            }
#pragma unroll
            for (int fn = 0; fn < 4; ++fn) {
                int col = wc * 64 + fn * 16 + lr;
                int idx = col * 64 + ((ks * 32 + kg4 * 8) ^ ((col & 7) << 3));
                b_h[fn] = *(const short8*)&Bh[idx];
                b_l[fn] = *(const short8*)&Bl[idx];
            }
#pragma unroll
            for (int fm = 0; fm < 4; ++fm)
#pragma unroll
                for (int fn = 0; fn < 4; ++fn) {
                    acc[fm][fn] = __builtin_amdgcn_mfma_f32_16x16x32_bf16(
                        a_h[fm], b_h[fn], acc[fm][fn], 0, 0, 0);
                    acc[fm][fn] = __builtin_amdgcn_mfma_f32_16x16x32_bf16(
                        a_h[fm], b_l[fn], acc[fm][fn], 0, 0, 0);
                    acc[fm][fn] = __builtin_amdgcn_mfma_f32_16x16x32_bf16(
                        a_l[fm], b_h[fn], acc[fm][fn], 0, 0, 0);
                }
        }
    }

    // ---- epilogue: C/D layout col=lane&15, row=(lane>>4)*4+reg
#pragma unroll
    for (int fm = 0; fm < 4; ++fm)
#pragma unroll
        for (int fn = 0; fn < 4; ++fn) {
            int col = n0 + wc * 64 + fn * 16 + lr;
#pragma unroll
            for (int j = 0; j < 4; ++j) {
                int row = m0 + wr * 64 + fm * 16 + kg4 * 4 + j;
                QKV[(size_t)row * QKVC + col] = acc[fm][fn][j];
            }
        }
}

// ================= Spatial attention (unchanged from round 10: verified fast) ==============
#define QDOT(JJ, SREG) do {                                                     \
    const float* kr_ = &Ks[k0 + (JJ)][l16];                                     \
    float4 ka_ = *(const float4*)(kr_);      float4 kb_ = *(const float4*)(kr_ + 4);  \
    float4 kc_ = *(const float4*)(kr_ + 8);  float4 kd_ = *(const float4*)(kr_ + 12); \
    float d_ = qa.x * ka_.x;                                                    \
    d_ = fmaf(qa.y, ka_.y, d_); d_ = fmaf(qa.z, ka_.z, d_); d_ = fmaf(qa.w, ka_.w, d_); \
    d_ = fmaf(qb.x, kb_.x, d_); d_ = fmaf(qb.y, kb_.y, d_); d_ = fmaf(qb.z, kb_.z, d_); d_ = fmaf(qb.w, kb_.w, d_); \
    d_ = fmaf(qc.x, kc_.x, d_); d_ = fmaf(qc.y, kc_.y, d_); d_ = fmaf(qc.z, kc_.z, d_); d_ = fmaf(qc.w, kc_.w, d_); \
    d_ = fmaf(qd.x, kd_.x, d_); d_ = fmaf(qd.y, kd_.y, d_); d_ = fmaf(qd.z, kd_.z, d_); d_ = fmaf(qd.w, kd_.w, d_); \
    d_ += __shfl_xor(d_, 1, 4);  d_ += __shfl_xor(d_, 2, 4);                    \
    SREG = d_ * SCALE;                                                          \
} while (0)

#define PVACC(JJ, P) do {                                                       \
    const float* vr_ = &Vs[k0 + (JJ)][l16];                                     \
    float4 va_ = *(const float4*)(vr_);      float4 vb_ = *(const float4*)(vr_ + 4);  \
    float4 vc_ = *(const float4*)(vr_ + 8);  float4 vd_ = *(const float4*)(vr_ + 12); \
    ac0.x = fmaf((P), va_.x, ac0.x); ac0.y = fmaf((P), va_.y, ac0.y);           \
    ac0.z = fmaf((P), va_.z, ac0.z); ac0.w = fmaf((P), va_.w, ac0.w);           \
    ac1.x = fmaf((P), vb_.x, ac1.x); ac1.y = fmaf((P), vb_.y, ac1.y);           \
    ac1.z = fmaf((P), vb_.z, ac1.z); ac1.w = fmaf((P), vb_.w, ac1.w);           \
    ac2.x = fmaf((P), vc_.x, ac2.x); ac2.y = fmaf((P), vc_.y, ac2.y);           \
    ac2.z = fmaf((P), vc_.z, ac2.z); ac2.w = fmaf((P), vc_.w, ac2.w);           \
    ac3.x = fmaf((P), vd_.x, ac3.x); ac3.y = fmaf((P), vd_.y, ac3.y);           \
    ac3.z = fmaf((P), vd_.z, ac3.z); ac3.w = fmaf((P), vd_.w, ac3.w);           \
} while (0)

__global__ __launch_bounds__(1024, 1) void attn_spatial(const float* __restrict__ QKV,
                                                        float* __restrict__ Out) {
    __shared__ float Ks[256][DH];
    __shared__ float Vs[256][DH];
    const int t    = threadIdx.x;
    const int nt   = blockIdx.x & 15;
    const int h    = (blockIdx.x >> 4) & 3;
    const int b    = blockIdx.x >> 6;
    const int base = nt * 256;
    const int l16  = (t & 3) * 16;
    const int row  = t >> 2;
    const size_t rowoff = (size_t)b * NTOK;

    const float* Kg = QKV + (rowoff + base) * QKVC + 512  + h * DH;
    const float* Vg = QKV + (rowoff + base) * QKVC + 1024 + h * DH;
    const float* Qg = QKV + (rowoff + base + row) * QKVC + h * DH + l16;

#pragma unroll
    for (int i = 0; i < 4; ++i) {
        int idx = t + 1024 * i;
        int r = idx >> 4, c4 = (idx & 15) << 2;
        *(float4*)&Ks[r][c4] = *(const float4*)(Kg + (size_t)r * QKVC + c4);
        *(float4*)&Vs[r][c4] = *(const float4*)(Vg + (size_t)r * QKVC + c4);
    }

    float4 qa = *(const float4*)(Qg);
    float4 qb = *(const float4*)(Qg + 4);
    float4 qc = *(const float4*)(Qg + 8);
    float4 qd = *(const float4*)(Qg + 12);

    float4 ac0 = make_float4(0.f, 0.f, 0.f, 0.f);
    float4 ac1 = ac0, ac2 = ac0, ac3 = ac0;
    float m = -INFINITY, lsum = 0.f;

    __syncthreads();

    for (int k0 = 0; k0 < 256; k0 += 8) {
        float s0, s1, s2, s3, s4, s5, s6, s7;
        QDOT(0, s0); QDOT(1, s1); QDOT(2, s2); QDOT(3, s3);
        QDOT(4, s4); QDOT(5, s5); QDOT(6, s6); QDOT(7, s7);

        float cmax = fmaxf(fmaxf(fmaxf(s0, s1), fmaxf(s2, s3)),
                           fmaxf(fmaxf(s4, s5), fmaxf(s6, s7)));
        float mn   = fmaxf(m, cmax);
        float corr = __expf(m - mn);
        s0 = __expf(s0 - mn); s1 = __expf(s1 - mn); s2 = __expf(s2 - mn); s3 = __expf(s3 - mn);
        s4 = __expf(s4 - mn); s5 = __expf(s5 - mn); s6 = __expf(s6 - mn); s7 = __expf(s7 - mn);
        float psum = ((s0 + s1) + (s2 + s3)) + ((s4 + s5) + (s6 + s7));
        lsum = fmaf(lsum, corr, psum);
        m = mn;
        ac0.x *= corr; ac0.y *= corr; ac0.z *= corr; ac0.w *= corr;
        ac1.x *= corr; ac1.y *= corr; ac1.z *= corr; ac1.w *= corr;
        ac2.x *= corr; ac2.y *= corr; ac2.z *= corr; ac2.w *= corr;
        ac3.x *= corr; ac3.y *= corr; ac3.z *= corr; ac3.w *= corr;

        PVACC(0, s0); PVACC(1, s1); PVACC(2, s2); PVACC(3, s3);
        PVACC(4, s4); PVACC(5, s5); PVACC(6, s6); PVACC(7, s7);
    }

    float inv = 1.f / lsum;
    float* op = Out + ((size_t)(b * 4 + h) * NTOK + base + row) * DH + l16;
    *(float4*)(op)      = make_float4(ac0.x * inv, ac0.y * inv, ac0.z * inv, ac0.w * inv);
    *(float4*)(op + 4)  = make_float4(ac1.x * inv, ac1.y * inv, ac1.z * inv, ac1.w * inv);
    *(float4*)(op + 8)  = make_float4(ac2.x * inv, ac2.y * inv, ac2.z * inv, ac2.w * inv);
    *(float4*)(op + 12) = make_float4(ac3.x * inv, ac3.y * inv, ac3.z * inv, ac3.w * inv);
}

// ================= Temporal attention (unchanged) =============
__global__ __launch_bounds__(256, 4) void attn_temporal(const float* __restrict__ QKV,
                                                        float* __restrict__ Out) {
    const int t    = threadIdx.x;
    const int l    = t & 3;
    const int row  = blockIdx.x * 64 + (t >> 2);
    const int tt   = row & 15;
    const int s    = (row >> 4) & 255;
    const int h    = (row >> 12) & 3;
    const int b    = row >> 14;
    const int head = 4 + h;
    const int token = s * 16 + tt;
    const size_t rowoff = (size_t)b * NTOK;

    const float* Qp = QKV + (rowoff + token) * QKVC + head * DH + l * 16;
    const float* Kb = QKV + (rowoff + s * 16) * QKVC + 512  + head * DH + l * 16;
    const float* Vb = QKV + (rowoff + s * 16) * QKVC + 1024 + head * DH + l * 16;

    float q[16];
#pragma unroll
    for (int c = 0; c < 16; c += 4) *(float4*)&q[c] = *(const float4*)(Qp + c);

    float sc[16];
    float mx = -INFINITY;
#pragma unroll
    for (int j = 0; j < 16; ++j) {
        const float* kr = Kb + (size_t)j * QKVC;
        float d = 0.f;
#pragma unroll
        for (int c = 0; c < 16; c += 4) {
            float4 kv = *(const float4*)(kr + c);
            d = fmaf(q[c], kv.x, d); d = fmaf(q[c+1], kv.y, d);
            d = fmaf(q[c+2], kv.z, d); d = fmaf(q[c+3], kv.w, d);
        }
        d += __shfl_xor(d, 1, 4);
        d += __shfl_xor(d, 2, 4);
        sc[j] = d * SCALE;
        mx = fmaxf(mx, sc[j]);
    }
    float lsum = 0.f;
#pragma unroll
    for (int j = 0; j < 16; ++j) { sc[j] = __expf(sc[j] - mx); lsum += sc[j]; }
    float inv = 1.f / lsum;

    float acc[16];
#pragma unroll
    for (int c = 0; c < 16; ++c) acc[c] = 0.f;
#pragma unroll
    for (int j = 0; j < 16; ++j) {
        const float* vr = Vb + (size_t)j * QKVC;
        float p = sc[j];
#pragma unroll
        for (int c = 0; c < 16; c += 4) {
            float4 vv = *(const float4*)(vr + c);
            acc[c]   = fmaf(p, vv.x, acc[c]);   acc[c+1] = fmaf(p, vv.y, acc[c+1]);
            acc[c+2] = fmaf(p, vv.z, acc[c+2]); acc[c+3] = fmaf(p, vv.w, acc[c+3]);
        }
    }
    float* op = Out + (size_t)(NBATCH * 4) * NTOK * DH
                    + ((size_t)(b * 4 + h) * NTOK + token) * DH + l * 16;
#pragma unroll
    for (int c = 0; c < 16; c += 4)
        *(float4*)(op + c) = make_float4(acc[c]*inv, acc[c+1]*inv, acc[c+2]*inv, acc[c+3]*inv);
}

extern "C" void kernel_launch(void* const* d_in, const int* in_sizes, int n_in,
                              void* d_out, int out_size, void* d_ws, size_t ws_size,
                              hipStream_t stream) {
    const float* x = (const float*)d_in[0];   // [8,4096,512] fp32
    const float* w = (const float*)d_in[1];   // [512,1536]  fp32
    float* out = (float*)d_out;               // [2,8,4,4096,64] fp32
    float* qkv = (float*)d_ws;                // 8*4096*1536*4 = 192 MiB scratch

    qkv_gemm_mfma<<<dim3(3072), 256, 0, stream>>>(x, w, qkv);
    attn_spatial<<<dim3(512), 1024, 0, stream>>>(qkv, out);
    attn_temporal<<<dim3(2048), 256, 0, stream>>>(qkv, out);
}